// Round 8
// baseline (118.392 us; speedup 1.0000x reference)
//
#include <hip/hip_runtime.h>
#include <stdint.h>

#define S_LEN 80
#define H_DIM 128
#define ROWS 10      // real lane rows per block (2560 = 256 blocks * 10)
#define MROWS 16     // padded MFMA M-tile
#define BLOCK_T 512  // 8 waves

#define NL2E  (-1.44269504088896f)   // -log2(e)
#define N2L2E (-2.88539008177793f)   // -2*log2(e)

typedef __bf16 bf16x8 __attribute__((ext_vector_type(8)));
typedef unsigned short u16x8 __attribute__((ext_vector_type(8)));
typedef unsigned short u16x4 __attribute__((ext_vector_type(4)));
typedef float f32x4 __attribute__((ext_vector_type(4)));

__device__ __forceinline__ float sigy(float y) {
    return __builtin_amdgcn_rcpf(1.0f + __builtin_amdgcn_exp2f(y));
}
__device__ __forceinline__ float tanhy(float y) {
    return 2.0f * __builtin_amdgcn_rcpf(1.0f + __builtin_amdgcn_exp2f(y)) - 1.0f;
}
__device__ __forceinline__ unsigned short bfbits(float f) {
    return __builtin_bit_cast(unsigned short, (__bf16)f);   // HW RNE cvt
}

// In-place accumulate; B straight from AGPRs (no a->v copies).
#define MFMA16(acc, va, wb) \
    asm("v_mfma_f32_16x16x32_bf16 %0, %1, %2, %0" : "+v"(acc) : "v"(va), "a"(wb))

// MFMA->VALU RAW fence: inline-asm MFMAs are invisible to the compiler's
// hazard recognizer; 24 wait states tied read-write to the accumulators.
#define MFMA_FENCE4(a, b, c, d) \
    asm volatile("s_nop 7\n\ts_nop 7\n\ts_nop 7" \
                 : "+v"(a), "+v"(b), "+v"(c), "+v"(d))

// One block = 10 lane rows through 80 LSTM steps. 8 waves; wave w owns hcols
// [w*16, w*16+16) with ALL FOUR gates so the cell is wave-local in registers.
// One barrier per step, double-buffered h/emb LDS. W frags AGPR-pinned.
//
// R8 (single-path, no branch — R6/R7's wave-parity branch double-inlined the
// loop body at the 256-reg cap and corrupted results; reverted):
//   hh(into xp, no g copy) -> fence -> cell-compute -> ih(s+1) -> cell-store.
// cell's transcendental latency tail drains under ih's 16 independent MFMAs.
// xp[s] is dead after hh, so hh accumulates in place (bit-identical values).
//
// Swizzle discipline: key = (row&7)<<4 spans BITS 4-6 -> XOR onto the FULL
// logical byte offset (incl. kt*64, bits 6-7), never onto a pre-XORed base.
__global__ __launch_bounds__(BLOCK_T, 2)
void lane_lstm(const float* __restrict__ lanes,
               const float* __restrict__ W_emb, const float* __restrict__ b_emb,
               const float* __restrict__ W_ih,  const float* __restrict__ W_hh,
               const float* __restrict__ b_ih,  const float* __restrict__ b_hh,
               float* __restrict__ out, int BL)
{
    __shared__ __align__(16) float ext_lds[S_LEN * ROWS * 5];           // 16000 B
    __shared__ __align__(16) unsigned short emb_lds[2][MROWS * H_DIM];  // 2x4096 B
    __shared__ __align__(16) unsigned short h_lds[2][MROWS * H_DIM];    // 2x4096 B
    __shared__ int valid_lds[MROWS];

    const int t    = threadIdx.x;
    const int lane = t & 63;
    const int wv   = t >> 6;
    const int row0 = blockIdx.x * ROWS;

    if (t < MROWS) valid_lds[t] = 1;
    {   // h0 = 0 (buffer 0)
        u16x4 z = {0, 0, 0, 0};
        *(u16x4*)((char*)&h_lds[0][0] + t * 8) = z;
    }
    __syncthreads();

    // ---- ext features (x,y,dx,dy,yaw) ----
    for (int p = t; p < S_LEN * ROWS; p += BLOCK_T) {
        int s = p / ROWS;
        int r = p - s * ROWS;
        int bl = row0 + r;
        float x = 0.f, y = 0.f, dx = 0.f, dy = 0.f;
        if (bl < BL) {
            const float* lp = lanes + ((size_t)s * BL + bl) * 2;
            x = lp[0]; y = lp[1];
            if (s > 0) {
                const float* lq = lanes + ((size_t)(s - 1) * BL + bl) * 2;
                dx = x - lq[0]; dy = y - lq[1];
            }
            if (__builtin_isnan(x) || __builtin_isnan(y)) valid_lds[r] = 0;
        }
        float* e = &ext_lds[p * 5];
        e[0] = x; e[1] = y; e[2] = dx; e[3] = dy; e[4] = atan2f(y, x);
    }

    // ---- wave-owned weight B-frags, PRE-SCALED, AGPR-pinned ----
    const int hcol = wv * 16 + (lane & 15);
    const int kb0  = (lane >> 4) << 3;
    f32x4 wih[4][4], whh[4][4];
    float bia[4];
    #pragma unroll
    for (int g = 0; g < 4; ++g) {
        const float sc = (g == 2) ? N2L2E : NL2E;
        bia[g] = (b_ih[g * H_DIM + hcol] + b_hh[g * H_DIM + hcol]) * sc;
        #pragma unroll
        for (int kt = 0; kt < 4; ++kt) {
            const float* pa = &W_ih[(size_t)(g * H_DIM + hcol) * H_DIM + kt * 32 + kb0];
            const float* pb = &W_hh[(size_t)(g * H_DIM + hcol) * H_DIM + kt * 32 + kb0];
            u16x8 ta, tb;
            #pragma unroll
            for (int j = 0; j < 8; ++j) { ta[j] = bfbits(pa[j] * sc); tb[j] = bfbits(pb[j] * sc); }
            wih[g][kt] = __builtin_bit_cast(f32x4, ta);
            whh[g][kt] = __builtin_bit_cast(f32x4, tb);
        }
    }
    #pragma unroll
    for (int g = 0; g < 4; ++g) {
        #pragma unroll
        for (int kt = 0; kt < 4; ++kt) {
            asm volatile("" : "+a"(wih[g][kt]));
            asm volatile("" : "+a"(whh[g][kt]));
        }
    }

    // ---- per-thread emb constants (thread t -> row t>>5, hcols (t&31)*4..+3) ----
    const int er  = t >> 5;
    const int ec0 = (t & 31) << 2;
    float wemb[4][5], bemb[4];
    #pragma unroll
    for (int j = 0; j < 4; ++j) {
        #pragma unroll
        for (int d = 0; d < 5; ++d) wemb[j][d] = W_emb[(ec0 + j) * 5 + d];
        bemb[j] = b_emb[ec0 + j];
    }
    const int ebyte = ((er << 8) + (ec0 << 1)) ^ ((er & 7) << 4);

    auto emb_store = [&](int s, int b) {
        float x0 = 0.f, x1 = 0.f, x2 = 0.f, x3 = 0.f, x4 = 0.f;
        if (er < ROWS && valid_lds[er] && row0 + er < BL) {
            const float* e = &ext_lds[(s * ROWS + er) * 5];
            x0 = e[0]; x1 = e[1]; x2 = e[2]; x3 = e[3]; x4 = e[4];
        }
        u16x4 ev;
        #pragma unroll
        for (int j = 0; j < 4; ++j) {
            float a = bemb[j];
            a += wemb[j][0] * x0; a += wemb[j][1] * x1; a += wemb[j][2] * x2;
            a += wemb[j][3] * x3; a += wemb[j][4] * x4;
            ev[j] = bfbits(fmaxf(a, 0.f));
        }
        *(u16x4*)((char*)&emb_lds[b][0] + ebyte) = ev;
    };

    const int arow  = lane & 15;
    const int akey  = (arow & 7) << 4;
    const int abase = (arow << 8) + ((lane >> 4) << 4);
    const int crow  = (lane >> 4) << 2;   // C/D (m89): row=(lane>>4)*4+i, col=lane&15

    __syncthreads();       // ext + valid + h0 ready
    emb_store(0, 0);
    __syncthreads();       // emb[0] visible

    // ---- prologue: xp = bias + emb[0] @ W_ih^T ----
    f32x4 xp0 = {bia[0], bia[0], bia[0], bia[0]};
    f32x4 xp1 = {bia[1], bia[1], bia[1], bia[1]};
    f32x4 xp2 = {bia[2], bia[2], bia[2], bia[2]};
    f32x4 xp3 = {bia[3], bia[3], bia[3], bia[3]};
    {
        const char* eb = (const char*)&emb_lds[0][0];
        #pragma unroll
        for (int kt = 0; kt < 4; ++kt) {
            bf16x8 ae = *(const bf16x8*)(eb + ((abase + kt * 64) ^ akey));
            MFMA16(xp0, ae, wih[0][kt]);
            MFMA16(xp1, ae, wih[1][kt]);
            MFMA16(xp2, ae, wih[2][kt]);
            MFMA16(xp3, ae, wih[3][kt]);
        }
    }
    emb_store(1, 1);
    __syncthreads();       // emb[1] visible

    float c0 = 0.f, c1 = 0.f, c2 = 0.f, c3 = 0.f;

    for (int s = 0; s < S_LEN; ++s) {
        const char* hb = (const char*)&h_lds[s & 1][0];
        const char* en = (const char*)&emb_lds[(s + 1) & 1][0];   // emb[s+1]

        // ---- hh GEMM: xp[s] += h[s] @ W_hh^T -> gates (in place) ----
        bf16x8 ah0 = *(const bf16x8*)(hb + ((abase + 0 * 64) ^ akey));
        bf16x8 ah1 = *(const bf16x8*)(hb + ((abase + 1 * 64) ^ akey));
        bf16x8 ah2 = *(const bf16x8*)(hb + ((abase + 2 * 64) ^ akey));
        bf16x8 ah3 = *(const bf16x8*)(hb + ((abase + 3 * 64) ^ akey));
        MFMA16(xp0, ah0, whh[0][0]); MFMA16(xp1, ah0, whh[1][0]);
        MFMA16(xp2, ah0, whh[2][0]); MFMA16(xp3, ah0, whh[3][0]);
        MFMA16(xp0, ah1, whh[0][1]); MFMA16(xp1, ah1, whh[1][1]);
        MFMA16(xp2, ah1, whh[2][1]); MFMA16(xp3, ah1, whh[3][1]);
        MFMA16(xp0, ah2, whh[0][2]); MFMA16(xp1, ah2, whh[1][2]);
        MFMA16(xp2, ah2, whh[2][2]); MFMA16(xp3, ah2, whh[3][2]);
        MFMA16(xp0, ah3, whh[0][3]); MFMA16(xp1, ah3, whh[1][3]);
        MFMA16(xp2, ah3, whh[2][3]); MFMA16(xp3, ah3, whh[3][3]);
        MFMA_FENCE4(xp0, xp1, xp2, xp3);   // asm-MFMA -> VALU g-read seam

        // ---- cell compute: issues early; latency drains under ih MFMAs ----
        float hv0, hv1, hv2, hv3;
        c0 = sigy(xp1[0]) * c0 + sigy(xp0[0]) * tanhy(xp2[0]);  hv0 = sigy(xp3[0]) * tanhy(c0 * N2L2E);
        c1 = sigy(xp1[1]) * c1 + sigy(xp0[1]) * tanhy(xp2[1]);  hv1 = sigy(xp3[1]) * tanhy(c1 * N2L2E);
        c2 = sigy(xp1[2]) * c2 + sigy(xp0[2]) * tanhy(xp2[2]);  hv2 = sigy(xp3[2]) * tanhy(c2 * N2L2E);
        c3 = sigy(xp1[3]) * c3 + sigy(xp0[3]) * tanhy(xp2[3]);  hv3 = sigy(xp3[3]) * tanhy(c3 * N2L2E);

        // ---- ih GEMM for step s+1 (independent of h and of the cell) ----
        if (s + 1 < S_LEN) {
            bf16x8 ae0 = *(const bf16x8*)(en + ((abase + 0 * 64) ^ akey));
            bf16x8 ae1 = *(const bf16x8*)(en + ((abase + 1 * 64) ^ akey));
            bf16x8 ae2 = *(const bf16x8*)(en + ((abase + 2 * 64) ^ akey));
            bf16x8 ae3 = *(const bf16x8*)(en + ((abase + 3 * 64) ^ akey));
            xp0 = (f32x4){bia[0], bia[0], bia[0], bia[0]};
            xp1 = (f32x4){bia[1], bia[1], bia[1], bia[1]};
            xp2 = (f32x4){bia[2], bia[2], bia[2], bia[2]};
            xp3 = (f32x4){bia[3], bia[3], bia[3], bia[3]};
            MFMA16(xp0, ae0, wih[0][0]); MFMA16(xp1, ae0, wih[1][0]);
            MFMA16(xp2, ae0, wih[2][0]); MFMA16(xp3, ae0, wih[3][0]);
            MFMA16(xp0, ae1, wih[0][1]); MFMA16(xp1, ae1, wih[1][1]);
            MFMA16(xp2, ae1, wih[2][1]); MFMA16(xp3, ae1, wih[3][1]);
            MFMA16(xp0, ae2, wih[0][2]); MFMA16(xp1, ae2, wih[1][2]);
            MFMA16(xp2, ae2, wih[2][2]); MFMA16(xp3, ae2, wih[3][2]);
            MFMA16(xp0, ae3, wih[0][3]); MFMA16(xp1, ae3, wih[1][3]);
            MFMA16(xp2, ae3, wih[2][3]); MFMA16(xp3, ae3, wih[3][3]);
            if (s + 2 < S_LEN) emb_store(s + 2, s & 1);
        }

        // ---- cell store: h -> bf16 LDS (and out at s=79) ----
        {
            char* hn = (char*)&h_lds[(s + 1) & 1][0];
            #pragma unroll
            for (int i = 0; i < 4; ++i) {
                const float hvi = (i == 0) ? hv0 : (i == 1) ? hv1 : (i == 2) ? hv2 : hv3;
                const int r = crow + i;
                const int byte = ((r << 8) + (hcol << 1)) ^ ((r & 7) << 4);
                *(unsigned short*)(hn + byte) = bfbits(hvi);
            }
            if (s == S_LEN - 1) {
                #pragma unroll
                for (int i = 0; i < 4; ++i) {
                    const float hvi = (i == 0) ? hv0 : (i == 1) ? hv1 : (i == 2) ? hv2 : hv3;
                    const int r = crow + i;
                    if (r < ROWS && row0 + r < BL)
                        out[(size_t)(row0 + r) * H_DIM + hcol] = hvi;
                }
            }
        }
        __syncthreads();   // one barrier/step
    }
}

extern "C" void kernel_launch(void* const* d_in, const int* in_sizes, int n_in,
                              void* d_out, int out_size, void* d_ws, size_t ws_size,
                              hipStream_t stream) {
    const float* lanes = (const float*)d_in[1];
    const float* W_emb = (const float*)d_in[2];
    const float* b_emb = (const float*)d_in[3];
    const float* W_ih  = (const float*)d_in[4];
    const float* W_hh  = (const float*)d_in[5];
    const float* b_ih  = (const float*)d_in[6];
    const float* b_hh  = (const float*)d_in[7];
    float* out = (float*)d_out;

    const int BL   = in_sizes[1] / (2 * S_LEN);   // 2560
    const int grid = (BL + ROWS - 1) / ROWS;      // 256 blocks -> 1 per CU

    lane_lstm<<<dim3(grid), dim3(BLOCK_T), 0, stream>>>(
        lanes, W_emb, b_emb, W_ih, W_hh, b_ih, b_hh, out, BL);
}

// Round 10
// 117.087 us; speedup vs baseline: 1.0111x; 1.0111x over previous
//
#include <hip/hip_runtime.h>
#include <stdint.h>

#define S_LEN 80
#define H_DIM 128
#define ROWS 10      // real lane rows per block (2560 = 256 blocks * 10)
#define MROWS 16     // padded MFMA M-tile
#define BLOCK_T 512  // 8 waves

#define NL2E  (-1.44269504088896f)   // -log2(e)
#define N2L2E (-2.88539008177793f)   // -2*log2(e)

typedef __bf16 bf16x8 __attribute__((ext_vector_type(8)));
typedef unsigned short u16x8 __attribute__((ext_vector_type(8)));
typedef unsigned short u16x4 __attribute__((ext_vector_type(4)));
typedef float f32x4 __attribute__((ext_vector_type(4)));

__device__ __forceinline__ float sigy(float y) {
    return __builtin_amdgcn_rcpf(1.0f + __builtin_amdgcn_exp2f(y));
}
__device__ __forceinline__ float tanhy(float y) {
    return 2.0f * __builtin_amdgcn_rcpf(1.0f + __builtin_amdgcn_exp2f(y)) - 1.0f;
}
__device__ __forceinline__ unsigned short bfbits(float f) {
    return __builtin_bit_cast(unsigned short, (__bf16)f);   // HW RNE cvt
}

// INTRINSIC MFMA (R9/R10): visible to the machine scheduler (latency modeled,
// hazard nops auto-inserted, VALU interleaved into the MFMA shadow) — the
// asm version made each GEMM an opaque block and the step's pipes ran
// sequentially (R8 counters: MFMA 27% + VALU 49% + LDS ~18% ≈ 100% additive).
// B operands stay in AGPRs via the pin below; gfx950 MFMA sources are
// VGPR-or-AGPR class, so no a->v copies are required.
#define MFMA(A, B, C) __builtin_amdgcn_mfma_f32_16x16x32_bf16((A), (B), (C), 0, 0, 0)
#define WB(W) __builtin_bit_cast(bf16x8, W)

// One block = 10 lane rows through 80 LSTM steps. 8 waves; wave w owns hcols
// [w*16, w*16+16) with ALL FOUR gates so the cell is wave-local in registers.
// One barrier per step, double-buffered h/emb LDS. Weights AGPR-pinned.
// Single code path (NO wave-divergent ordering: R6/R7's branch at the 256-reg
// cap miscompiled). Last step peeled (no per-step s==79 branch).
// R10 fix vs R9: bias splats hoisted into named f32x4 (braced init inside a
// macro arg doesn't preprocess; also drops 4 splat-rebuilds per step).
//
// Swizzle discipline: key = (row&7)<<4 spans BITS 4-6 -> XOR onto the FULL
// logical byte offset (incl. kt*64, bits 6-7), never onto a pre-XORed base.
__global__ __launch_bounds__(BLOCK_T, 2)
void lane_lstm(const float* __restrict__ lanes,
               const float* __restrict__ W_emb, const float* __restrict__ b_emb,
               const float* __restrict__ W_ih,  const float* __restrict__ W_hh,
               const float* __restrict__ b_ih,  const float* __restrict__ b_hh,
               float* __restrict__ out, int BL)
{
    __shared__ __align__(16) float ext_lds[S_LEN * ROWS * 5];           // 16000 B
    __shared__ __align__(16) unsigned short emb_lds[2][MROWS * H_DIM];  // 2x4096 B
    __shared__ __align__(16) unsigned short h_lds[2][MROWS * H_DIM];    // 2x4096 B
    __shared__ int valid_lds[MROWS];

    const int t    = threadIdx.x;
    const int lane = t & 63;
    const int wv   = t >> 6;
    const int row0 = blockIdx.x * ROWS;

    if (t < MROWS) valid_lds[t] = 1;
    {   // h0 = 0 (buffer 0)
        u16x4 z = {0, 0, 0, 0};
        *(u16x4*)((char*)&h_lds[0][0] + t * 8) = z;
    }
    __syncthreads();

    // ---- ext features (x,y,dx,dy,yaw) ----
    for (int p = t; p < S_LEN * ROWS; p += BLOCK_T) {
        int s = p / ROWS;
        int r = p - s * ROWS;
        int bl = row0 + r;
        float x = 0.f, y = 0.f, dx = 0.f, dy = 0.f;
        if (bl < BL) {
            const float* lp = lanes + ((size_t)s * BL + bl) * 2;
            x = lp[0]; y = lp[1];
            if (s > 0) {
                const float* lq = lanes + ((size_t)(s - 1) * BL + bl) * 2;
                dx = x - lq[0]; dy = y - lq[1];
            }
            if (__builtin_isnan(x) || __builtin_isnan(y)) valid_lds[r] = 0;
        }
        float* e = &ext_lds[p * 5];
        e[0] = x; e[1] = y; e[2] = dx; e[3] = dy; e[4] = atan2f(y, x);
    }

    // ---- wave-owned weight B-frags, PRE-SCALED, AGPR-pinned ----
    // B-frag: col = g*128 + wv*16 + (lane&15), k = kt*32 + (lane>>4)*8 + j.
    // Gate scale: i,f,o -> -log2e ; g -> -2log2e (exp2-direct nonlinearities).
    const int hcol = wv * 16 + (lane & 15);
    const int kb0  = (lane >> 4) << 3;
    f32x4 wih[4][4], whh[4][4];
    float bia[4];
    #pragma unroll
    for (int g = 0; g < 4; ++g) {
        const float sc = (g == 2) ? N2L2E : NL2E;
        bia[g] = (b_ih[g * H_DIM + hcol] + b_hh[g * H_DIM + hcol]) * sc;
        #pragma unroll
        for (int kt = 0; kt < 4; ++kt) {
            const float* pa = &W_ih[(size_t)(g * H_DIM + hcol) * H_DIM + kt * 32 + kb0];
            const float* pb = &W_hh[(size_t)(g * H_DIM + hcol) * H_DIM + kt * 32 + kb0];
            u16x8 ta, tb;
            #pragma unroll
            for (int j = 0; j < 8; ++j) { ta[j] = bfbits(pa[j] * sc); tb[j] = bfbits(pb[j] * sc); }
            wih[g][kt] = __builtin_bit_cast(f32x4, ta);
            whh[g][kt] = __builtin_bit_cast(f32x4, tb);
        }
    }
    #pragma unroll
    for (int g = 0; g < 4; ++g) {
        #pragma unroll
        for (int kt = 0; kt < 4; ++kt) {
            asm volatile("" : "+a"(wih[g][kt]));   // pin to AGPR file
            asm volatile("" : "+a"(whh[g][kt]));
        }
    }
    // named bias splats (macro-safe; built once, reused every step)
    f32x4 bv0, bv1, bv2, bv3;
    bv0[0] = bia[0]; bv0[1] = bia[0]; bv0[2] = bia[0]; bv0[3] = bia[0];
    bv1[0] = bia[1]; bv1[1] = bia[1]; bv1[2] = bia[1]; bv1[3] = bia[1];
    bv2[0] = bia[2]; bv2[1] = bia[2]; bv2[2] = bia[2]; bv2[3] = bia[2];
    bv3[0] = bia[3]; bv3[1] = bia[3]; bv3[2] = bia[3]; bv3[3] = bia[3];

    // ---- per-thread emb constants (thread t -> row t>>5, hcols (t&31)*4..+3) ----
    const int er  = t >> 5;
    const int ec0 = (t & 31) << 2;
    float wemb[4][5], bemb[4];
    #pragma unroll
    for (int j = 0; j < 4; ++j) {
        #pragma unroll
        for (int d = 0; d < 5; ++d) wemb[j][d] = W_emb[(ec0 + j) * 5 + d];
        bemb[j] = b_emb[ec0 + j];
    }
    const int ebyte = ((er << 8) + (ec0 << 1)) ^ ((er & 7) << 4);

    auto emb_store = [&](int s, int b) {
        float x0 = 0.f, x1 = 0.f, x2 = 0.f, x3 = 0.f, x4 = 0.f;
        if (er < ROWS && valid_lds[er] && row0 + er < BL) {
            const float* e = &ext_lds[(s * ROWS + er) * 5];
            x0 = e[0]; x1 = e[1]; x2 = e[2]; x3 = e[3]; x4 = e[4];
        }
        u16x4 ev;
        #pragma unroll
        for (int j = 0; j < 4; ++j) {
            float a = bemb[j];
            a += wemb[j][0] * x0; a += wemb[j][1] * x1; a += wemb[j][2] * x2;
            a += wemb[j][3] * x3; a += wemb[j][4] * x4;
            ev[j] = bfbits(fmaxf(a, 0.f));
        }
        *(u16x4*)((char*)&emb_lds[b][0] + ebyte) = ev;
    };

    const int arow  = lane & 15;
    const int akey  = (arow & 7) << 4;
    const int abase = (arow << 8) + ((lane >> 4) << 4);
    const int crow  = (lane >> 4) << 2;   // C/D (m89): row=(lane>>4)*4+i, col=lane&15

    __syncthreads();       // ext + valid + h0 ready
    emb_store(0, 0);
    __syncthreads();       // emb[0] visible

    // ---- prologue: xp = bias + emb[0] @ W_ih^T ----
    f32x4 xp0, xp1, xp2, xp3;
    {
        const char* eb = (const char*)&emb_lds[0][0];
        bf16x8 e0 = *(const bf16x8*)(eb + ((abase + 0 * 64) ^ akey));
        bf16x8 e1 = *(const bf16x8*)(eb + ((abase + 1 * 64) ^ akey));
        bf16x8 e2 = *(const bf16x8*)(eb + ((abase + 2 * 64) ^ akey));
        bf16x8 e3 = *(const bf16x8*)(eb + ((abase + 3 * 64) ^ akey));
        xp0 = MFMA(e0, WB(wih[0][0]), bv0);
        xp0 = MFMA(e1, WB(wih[0][1]), xp0);
        xp0 = MFMA(e2, WB(wih[0][2]), xp0);
        xp0 = MFMA(e3, WB(wih[0][3]), xp0);
        xp1 = MFMA(e0, WB(wih[1][0]), bv1);
        xp1 = MFMA(e1, WB(wih[1][1]), xp1);
        xp1 = MFMA(e2, WB(wih[1][2]), xp1);
        xp1 = MFMA(e3, WB(wih[1][3]), xp1);
        xp2 = MFMA(e0, WB(wih[2][0]), bv2);
        xp2 = MFMA(e1, WB(wih[2][1]), xp2);
        xp2 = MFMA(e2, WB(wih[2][2]), xp2);
        xp2 = MFMA(e3, WB(wih[2][3]), xp2);
        xp3 = MFMA(e0, WB(wih[3][0]), bv3);
        xp3 = MFMA(e1, WB(wih[3][1]), xp3);
        xp3 = MFMA(e2, WB(wih[3][2]), xp3);
        xp3 = MFMA(e3, WB(wih[3][3]), xp3);
    }
    emb_store(1, 1);
    __syncthreads();       // emb[1] visible

    float c0 = 0.f, c1 = 0.f, c2 = 0.f, c3 = 0.f;

    for (int s = 0; s < S_LEN - 1; ++s) {
        const char* hb = (const char*)&h_lds[s & 1][0];
        const char* en = (const char*)&emb_lds[(s + 1) & 1][0];   // emb[s+1]

        // ---- hh GEMM: g = xp[s] + h[s] @ W_hh^T (SSA, no copy) ----
        bf16x8 ah0 = *(const bf16x8*)(hb + ((abase + 0 * 64) ^ akey));
        bf16x8 ah1 = *(const bf16x8*)(hb + ((abase + 1 * 64) ^ akey));
        bf16x8 ah2 = *(const bf16x8*)(hb + ((abase + 2 * 64) ^ akey));
        bf16x8 ah3 = *(const bf16x8*)(hb + ((abase + 3 * 64) ^ akey));
        f32x4 g0 = MFMA(ah0, WB(whh[0][0]), xp0);
        g0 = MFMA(ah1, WB(whh[0][1]), g0);
        g0 = MFMA(ah2, WB(whh[0][2]), g0);
        g0 = MFMA(ah3, WB(whh[0][3]), g0);
        f32x4 g1 = MFMA(ah0, WB(whh[1][0]), xp1);
        g1 = MFMA(ah1, WB(whh[1][1]), g1);
        g1 = MFMA(ah2, WB(whh[1][2]), g1);
        g1 = MFMA(ah3, WB(whh[1][3]), g1);
        f32x4 g2 = MFMA(ah0, WB(whh[2][0]), xp2);
        g2 = MFMA(ah1, WB(whh[2][1]), g2);
        g2 = MFMA(ah2, WB(whh[2][2]), g2);
        g2 = MFMA(ah3, WB(whh[2][3]), g2);
        f32x4 g3 = MFMA(ah0, WB(whh[3][0]), xp3);
        g3 = MFMA(ah1, WB(whh[3][1]), g3);
        g3 = MFMA(ah2, WB(whh[3][2]), g3);
        g3 = MFMA(ah3, WB(whh[3][3]), g3);

        // ---- ih GEMM for step s+1, WOVEN with the cell: each gate's 4-MFMA
        // chain alternates with one cell element's transcendental chain.
        // The scheduler (intrinsics => latency modeled) dovetails the pipes. ----
        bf16x8 ae0 = *(const bf16x8*)(en + ((abase + 0 * 64) ^ akey));
        bf16x8 ae1 = *(const bf16x8*)(en + ((abase + 1 * 64) ^ akey));
        bf16x8 ae2 = *(const bf16x8*)(en + ((abase + 2 * 64) ^ akey));
        bf16x8 ae3 = *(const bf16x8*)(en + ((abase + 3 * 64) ^ akey));
        float hv0, hv1, hv2, hv3;

        xp0 = MFMA(ae0, WB(wih[0][0]), bv0);
        xp0 = MFMA(ae1, WB(wih[0][1]), xp0);
        xp0 = MFMA(ae2, WB(wih[0][2]), xp0);
        xp0 = MFMA(ae3, WB(wih[0][3]), xp0);
        c0 = sigy(g1[0]) * c0 + sigy(g0[0]) * tanhy(g2[0]);  hv0 = sigy(g3[0]) * tanhy(c0 * N2L2E);

        xp1 = MFMA(ae0, WB(wih[1][0]), bv1);
        xp1 = MFMA(ae1, WB(wih[1][1]), xp1);
        xp1 = MFMA(ae2, WB(wih[1][2]), xp1);
        xp1 = MFMA(ae3, WB(wih[1][3]), xp1);
        c1 = sigy(g1[1]) * c1 + sigy(g0[1]) * tanhy(g2[1]);  hv1 = sigy(g3[1]) * tanhy(c1 * N2L2E);

        xp2 = MFMA(ae0, WB(wih[2][0]), bv2);
        xp2 = MFMA(ae1, WB(wih[2][1]), xp2);
        xp2 = MFMA(ae2, WB(wih[2][2]), xp2);
        xp2 = MFMA(ae3, WB(wih[2][3]), xp2);
        c2 = sigy(g1[2]) * c2 + sigy(g0[2]) * tanhy(g2[2]);  hv2 = sigy(g3[2]) * tanhy(c2 * N2L2E);

        xp3 = MFMA(ae0, WB(wih[3][0]), bv3);
        xp3 = MFMA(ae1, WB(wih[3][1]), xp3);
        xp3 = MFMA(ae2, WB(wih[3][2]), xp3);
        xp3 = MFMA(ae3, WB(wih[3][3]), xp3);
        c3 = sigy(g1[3]) * c3 + sigy(g0[3]) * tanhy(g2[3]);  hv3 = sigy(g3[3]) * tanhy(c3 * N2L2E);

        if (s + 2 < S_LEN) emb_store(s + 2, s & 1);

        // ---- h -> bf16 LDS (next buffer) ----
        {
            char* hn = (char*)&h_lds[(s + 1) & 1][0];
            #pragma unroll
            for (int i = 0; i < 4; ++i) {
                const float hvi = (i == 0) ? hv0 : (i == 1) ? hv1 : (i == 2) ? hv2 : hv3;
                const int r = crow + i;
                const int byte = ((r << 8) + (hcol << 1)) ^ ((r & 7) << 4);
                *(unsigned short*)(hn + byte) = bfbits(hvi);
            }
        }
        __syncthreads();   // one barrier/step
    }

    // ---- peeled final step s = S_LEN-1: hh + cell + global out ----
    {
        const char* hb = (const char*)&h_lds[(S_LEN - 1) & 1][0];
        bf16x8 ah0 = *(const bf16x8*)(hb + ((abase + 0 * 64) ^ akey));
        bf16x8 ah1 = *(const bf16x8*)(hb + ((abase + 1 * 64) ^ akey));
        bf16x8 ah2 = *(const bf16x8*)(hb + ((abase + 2 * 64) ^ akey));
        bf16x8 ah3 = *(const bf16x8*)(hb + ((abase + 3 * 64) ^ akey));
        f32x4 g0 = MFMA(ah0, WB(whh[0][0]), xp0);
        g0 = MFMA(ah1, WB(whh[0][1]), g0);
        g0 = MFMA(ah2, WB(whh[0][2]), g0);
        g0 = MFMA(ah3, WB(whh[0][3]), g0);
        f32x4 g1 = MFMA(ah0, WB(whh[1][0]), xp1);
        g1 = MFMA(ah1, WB(whh[1][1]), g1);
        g1 = MFMA(ah2, WB(whh[1][2]), g1);
        g1 = MFMA(ah3, WB(whh[1][3]), g1);
        f32x4 g2 = MFMA(ah0, WB(whh[2][0]), xp2);
        g2 = MFMA(ah1, WB(whh[2][1]), g2);
        g2 = MFMA(ah2, WB(whh[2][2]), g2);
        g2 = MFMA(ah3, WB(whh[2][3]), g2);
        f32x4 g3 = MFMA(ah0, WB(whh[3][0]), xp3);
        g3 = MFMA(ah1, WB(whh[3][1]), g3);
        g3 = MFMA(ah2, WB(whh[3][2]), g3);
        g3 = MFMA(ah3, WB(whh[3][3]), g3);

        float hv0, hv1, hv2, hv3;
        c0 = sigy(g1[0]) * c0 + sigy(g0[0]) * tanhy(g2[0]);  hv0 = sigy(g3[0]) * tanhy(c0 * N2L2E);
        c1 = sigy(g1[1]) * c1 + sigy(g0[1]) * tanhy(g2[1]);  hv1 = sigy(g3[1]) * tanhy(c1 * N2L2E);
        c2 = sigy(g1[2]) * c2 + sigy(g0[2]) * tanhy(g2[2]);  hv2 = sigy(g3[2]) * tanhy(c2 * N2L2E);
        c3 = sigy(g1[3]) * c3 + sigy(g0[3]) * tanhy(g2[3]);  hv3 = sigy(g3[3]) * tanhy(c3 * N2L2E);

        #pragma unroll
        for (int i = 0; i < 4; ++i) {
            const float hvi = (i == 0) ? hv0 : (i == 1) ? hv1 : (i == 2) ? hv2 : hv3;
            const int r = crow + i;
            if (r < ROWS && row0 + r < BL)
                out[(size_t)(row0 + r) * H_DIM + hcol] = hvi;
        }
    }
}

extern "C" void kernel_launch(void* const* d_in, const int* in_sizes, int n_in,
                              void* d_out, int out_size, void* d_ws, size_t ws_size,
                              hipStream_t stream) {
    const float* lanes = (const float*)d_in[1];
    const float* W_emb = (const float*)d_in[2];
    const float* b_emb = (const float*)d_in[3];
    const float* W_ih  = (const float*)d_in[4];
    const float* W_hh  = (const float*)d_in[5];
    const float* b_ih  = (const float*)d_in[6];
    const float* b_hh  = (const float*)d_in[7];
    float* out = (float*)d_out;

    const int BL   = in_sizes[1] / (2 * S_LEN);   // 2560
    const int grid = (BL + ROWS - 1) / ROWS;      // 256 blocks -> 1 per CU

    lane_lstm<<<dim3(grid), dim3(BLOCK_T), 0, stream>>>(
        lanes, W_emb, b_emb, W_ih, W_hh, b_ih, b_hh, out, BL);
}